// Round 1
// baseline (1171.236 us; speedup 1.0000x reference)
//
#include <hip/hip_runtime.h>

#define N 8192
#define DIN 512
#define DOUT 256
#define ALPHA 0.2f
#define NEG_INF -9.0e15f

// Kernel 1: h = X@W + b, fused el = h@a_l, er = h@a_r.
// grid N/32 = 256 blocks x 256 threads; 32 rows of h per block.
__global__ __launch_bounds__(256) void gat_h_kernel(
        const float* __restrict__ X, const float* __restrict__ W,
        const float* __restrict__ b, const float* __restrict__ a,
        float* __restrict__ h, float* __restrict__ el, float* __restrict__ er)
{
    __shared__ float XsT[32][33];   // [kk][r], +1 pad
    __shared__ float Ws[32][256];   // [kk][c]
    const int t = threadIdx.x;
    const int i0 = blockIdx.x * 32;
    const int c0 = (t & 63) * 4;    // 4 cols per thread
    const int r0 = (t >> 6) * 8;    // 8 rows per thread (4 waves x 8 = 32)
    float acc[8][4];
    #pragma unroll
    for (int r = 0; r < 8; ++r)
        #pragma unroll
        for (int c = 0; c < 4; ++c) acc[r][c] = 0.f;

    const int xr = t >> 5, xk = t & 31;
    for (int k0 = 0; k0 < DIN; k0 += 32) {
        #pragma unroll
        for (int m = 0; m < 4; ++m)
            XsT[xk][xr + m * 8] = X[(i0 + xr + m * 8) * DIN + k0 + xk];
        #pragma unroll 8
        for (int m = 0; m < 32; ++m)
            Ws[m][t] = W[(k0 + m) * DOUT + t];
        __syncthreads();
        #pragma unroll
        for (int kk = 0; kk < 32; ++kk) {
            const float4 w4 = *(const float4*)&Ws[kk][c0];
            #pragma unroll
            for (int rr = 0; rr < 8; ++rr) {
                const float x = XsT[kk][r0 + rr];  // wave-uniform -> LDS broadcast
                acc[rr][0] = fmaf(x, w4.x, acc[rr][0]);
                acc[rr][1] = fmaf(x, w4.y, acc[rr][1]);
                acc[rr][2] = fmaf(x, w4.z, acc[rr][2]);
                acc[rr][3] = fmaf(x, w4.w, acc[rr][3]);
            }
        }
        __syncthreads();
    }
    const float4 b4  = *(const float4*)&b[c0];
    const float4 al4 = *(const float4*)&a[c0];
    const float4 ar4 = *(const float4*)&a[DOUT + c0];
    #pragma unroll
    for (int rr = 0; rr < 8; ++rr) {
        float4 hv;
        hv.x = acc[rr][0] + b4.x;
        hv.y = acc[rr][1] + b4.y;
        hv.z = acc[rr][2] + b4.z;
        hv.w = acc[rr][3] + b4.w;
        *(float4*)&h[(i0 + r0 + rr) * DOUT + c0] = hv;
        // fused el/er: each wave covers all 256 cols of its rows
        float vl = hv.x * al4.x + hv.y * al4.y + hv.z * al4.z + hv.w * al4.w;
        float vr = hv.x * ar4.x + hv.y * ar4.y + hv.z * ar4.z + hv.w * ar4.w;
        #pragma unroll
        for (int off = 32; off > 0; off >>= 1) {
            vl += __shfl_xor(vl, off);
            vr += __shfl_xor(vr, off);
        }
        if ((t & 63) == 0) { el[i0 + r0 + rr] = vl; er[i0 + r0 + rr] = vr; }
    }
}

// Kernel 2: fused masked-softmax + aggregation, no max-subtraction needed
// (scores bounded; exp(-9e15)=0 handles the mask). 32 rows per block,
// j streamed in tiles of 64. grid N/32 = 256 blocks x 512 threads.
__global__ __launch_bounds__(512) void gat_attn_kernel(
        const int* __restrict__ adj, const float* __restrict__ el,
        const float* __restrict__ er, const float* __restrict__ ab,
        const float* __restrict__ h, float* __restrict__ out)
{
    __shared__ float PsT[64][33];   // [j][r], stride 33 -> 2-way-max bank alias (free)
    __shared__ float el_s[32];
    __shared__ float linv_s[32];
    __shared__ float Lpart[16][32];
    const int t = threadIdx.x;
    const int i0 = blockIdx.x * 32;
    const float bias = ab[0];
    if (t < 32) el_s[t] = el[i0 + t];
    __syncthreads();

    const int c0 = (t & 63) * 4;    // 4 cols per thread
    const int r0 = (t >> 6) * 4;    // 4 rows per thread (8 waves x 4 = 32)
    const int lr = t & 31, ljg = t >> 5;
    const int sj = t & 63;          // score-phase j lane
    const int sr = t >> 6;          // score-phase row base
    float acc[4][4];
    #pragma unroll
    for (int r = 0; r < 4; ++r)
        #pragma unroll
        for (int c = 0; c < 4; ++c) acc[r][c] = 0.f;
    float lpart = 0.f;

    for (int j0 = 0; j0 < N; j0 += 64) {
        // P tile: p[r][j] = exp(adj ? lrelu(el_i + er_j + bias) : -inf)
        #pragma unroll
        for (int m = 0; m < 4; ++m) {
            const int r = sr + m * 8;
            const int av = adj[(i0 + r) * N + j0 + sj];   // coalesced along j
            float v = el_s[r] + er[j0 + sj] + bias;
            v = v > 0.f ? v : ALPHA * v;
            const float s = av > 0 ? v : NEG_INF;
            PsT[sj][r] = __expf(s);
        }
        __syncthreads();
        // per-row denominator partials (private slot per thread, no extra sync)
        #pragma unroll
        for (int k = 0; k < 4; ++k) lpart += PsT[ljg * 4 + k][lr];
        // acc[32 x 256] += P[32 x 64] @ H[64 x 256], register-blocked 4x4
        #pragma unroll 4
        for (int j = 0; j < 64; ++j) {
            const float4 hv = *(const float4*)&h[(j0 + j) * DOUT + c0];
            #pragma unroll
            for (int rr = 0; rr < 4; ++rr) {
                const float p = PsT[j][r0 + rr];   // wave-uniform broadcast
                acc[rr][0] = fmaf(p, hv.x, acc[rr][0]);
                acc[rr][1] = fmaf(p, hv.y, acc[rr][1]);
                acc[rr][2] = fmaf(p, hv.z, acc[rr][2]);
                acc[rr][3] = fmaf(p, hv.w, acc[rr][3]);
            }
        }
        __syncthreads();
    }
    Lpart[ljg][lr] = lpart;
    __syncthreads();
    if (t < 32) {
        float l = 0.f;
        #pragma unroll
        for (int g = 0; g < 16; ++g) l += Lpart[g][t];
        linv_s[t] = 1.0f / l;
    }
    __syncthreads();
    #pragma unroll
    for (int rr = 0; rr < 4; ++rr) {
        const float linv = linv_s[r0 + rr];
        float4 o;
        o.x = acc[rr][0] * linv;
        o.y = acc[rr][1] * linv;
        o.z = acc[rr][2] * linv;
        o.w = acc[rr][3] * linv;
        *(float4*)&out[(i0 + r0 + rr) * DOUT + c0] = o;
    }
}

extern "C" void kernel_launch(void* const* d_in, const int* in_sizes, int n_in,
                              void* d_out, int out_size, void* d_ws, size_t ws_size,
                              hipStream_t stream) {
    const int*   adj = (const int*)  d_in[0];
    const float* X   = (const float*)d_in[1];
    const float* W   = (const float*)d_in[2];
    const float* b   = (const float*)d_in[3];
    const float* a   = (const float*)d_in[4];
    const float* ab  = (const float*)d_in[5];
    float* out = (float*)d_out;
    float* h   = (float*)d_ws;                  // 8192*256 fp32 = 8 MB
    float* el  = h + (size_t)N * DOUT;          // +32 KB
    float* er  = el + N;                        // +32 KB

    gat_h_kernel<<<dim3(N / 32), dim3(256), 0, stream>>>(X, W, b, a, h, el, er);
    gat_attn_kernel<<<dim3(N / 32), dim3(512), 0, stream>>>(adj, el, er, ab, h, out);
}

// Round 2
// 653.546 us; speedup vs baseline: 1.7921x; 1.7921x over previous
//
#include <hip/hip_runtime.h>

#define N 8192
#define DIN 512
#define DOUT 256
#define ALPHA 0.2f
#define NEG_INF -9.0e15f

typedef __attribute__((ext_vector_type(8))) short bf16x8;
typedef __attribute__((ext_vector_type(4))) float f32x4;

__device__ __forceinline__ unsigned f2bf_u(float f) {
    unsigned u = __builtin_bit_cast(unsigned, f);
    return (u + 0x7fffu + ((u >> 16) & 1u)) >> 16;   // RNE bf16
}
__device__ __forceinline__ unsigned pack2bf(float lo, float hi) {
    return f2bf_u(lo) | (f2bf_u(hi) << 16);
}

union U4BF8 { uint4 u; bf16x8 v; };

// Kernel 0: W (fp32 [512][256]) -> WB bf16 in MFMA-B layout ((k>>3)*256+c)*8+(k&7)
__global__ __launch_bounds__(256) void wb_kernel(const float* __restrict__ W,
                                                 ushort* __restrict__ WB) {
    const int gid4 = (blockIdx.x * 256 + threadIdx.x) * 4;
    const float4 w4 = *(const float4*)&W[gid4];
    const int k = gid4 >> 8, c = gid4 & 255;
    const int base = (k >> 3) * 2048 + (k & 7);
    WB[base + (c + 0) * 8] = (ushort)f2bf_u(w4.x);
    WB[base + (c + 1) * 8] = (ushort)f2bf_u(w4.y);
    WB[base + (c + 2) * 8] = (ushort)f2bf_u(w4.z);
    WB[base + (c + 3) * 8] = (ushort)f2bf_u(w4.w);
}

// Kernel 1: h = X@W + b via MFMA; fused el/er; h written as bf16 in B-layout (hB).
// grid 128 x 256 thr (4 waves); 64 rows/block, wave w -> rows i0+w*16, all 256 cols.
__global__ __launch_bounds__(256) void h_kernel(
        const float* __restrict__ X, const ushort* __restrict__ WB,
        const float* __restrict__ bvec, const float* __restrict__ a,
        ushort* __restrict__ hB, float* __restrict__ el, float* __restrict__ er)
{
    __shared__ ushort XA[64 * 40];          // 64 rows x 32 k bf16, stride 40 elems (80B)
    const int t = threadIdx.x;
    const int i0 = blockIdx.x * 64;
    const int w = t >> 6, l = t & 63, q = l >> 4, n = l & 15;
    f32x4 acc[16];
    #pragma unroll
    for (int ct = 0; ct < 16; ++ct) acc[ct] = (f32x4){0.f, 0.f, 0.f, 0.f};
    const int sr = t >> 2, sc = (t & 3) * 8;

    for (int k0 = 0; k0 < DIN; k0 += 32) {
        const float4 x0 = *(const float4*)&X[(i0 + sr) * DIN + k0 + sc];
        const float4 x1 = *(const float4*)&X[(i0 + sr) * DIN + k0 + sc + 4];
        uint4 pk;
        pk.x = pack2bf(x0.x, x0.y); pk.y = pack2bf(x0.z, x0.w);
        pk.z = pack2bf(x1.x, x1.y); pk.w = pack2bf(x1.z, x1.w);
        __syncthreads();
        *(uint4*)&XA[sr * 40 + sc] = pk;
        __syncthreads();
        const bf16x8 af = *(const bf16x8*)&XA[(w * 16 + n) * 40 + q * 8];
        const ushort* wbp = WB + ((k0 >> 3) + q) * 2048 + n * 8;
        #pragma unroll
        for (int ct = 0; ct < 16; ++ct) {
            const bf16x8 bf = *(const bf16x8*)&wbp[ct * 128];
            acc[ct] = __builtin_amdgcn_mfma_f32_16x16x32_bf16(af, bf, acc[ct], 0, 0, 0);
        }
    }
    // epilogue: +b, el/er partials, hB write
    float pl[4] = {0.f, 0.f, 0.f, 0.f}, pr[4] = {0.f, 0.f, 0.f, 0.f};
    // hB elem addr for row i=i0+w*16+q*4+reg, col ct*16+n:
    //   (i>>3)*2048 + ct*128 + n*8 + (q&1)*4 + reg
    const int hbase = (blockIdx.x * 8 + w * 2 + (q >> 1)) * 2048 + n * 8 + (q & 1) * 4;
    #pragma unroll
    for (int ct = 0; ct < 16; ++ct) {
        const float bb = bvec[ct * 16 + n];
        const float al = a[ct * 16 + n];
        const float ar = a[DOUT + ct * 16 + n];
        float v0 = acc[ct][0] + bb, v1 = acc[ct][1] + bb;
        float v2 = acc[ct][2] + bb, v3 = acc[ct][3] + bb;
        pl[0] += v0 * al; pl[1] += v1 * al; pl[2] += v2 * al; pl[3] += v3 * al;
        pr[0] += v0 * ar; pr[1] += v1 * ar; pr[2] += v2 * ar; pr[3] += v3 * ar;
        ushort4 hp;
        hp.x = (ushort)f2bf_u(v0); hp.y = (ushort)f2bf_u(v1);
        hp.z = (ushort)f2bf_u(v2); hp.w = (ushort)f2bf_u(v3);
        *(ushort4*)&hB[hbase + ct * 128] = hp;
    }
    #pragma unroll
    for (int r = 0; r < 4; ++r) {
        #pragma unroll
        for (int off = 1; off < 16; off <<= 1) {
            pl[r] += __shfl_xor(pl[r], off);
            pr[r] += __shfl_xor(pr[r], off);
        }
    }
    if (n == 0) {
        const int row = i0 + w * 16 + q * 4;
        #pragma unroll
        for (int r = 0; r < 4; ++r) { el[row + r] = pl[r]; er[row + r] = pr[r]; }
    }
}

// Kernel 2: fused masked-softmax attention aggregate via MFMA.
// grid 256 x 512 thr (8 waves): row-group rg = w>>2 (16 rows), j-quarter jq = w&3.
// A-fragments of P computed in registers (adj -> score -> exp -> bf16), B from hB (L2).
__global__ __launch_bounds__(512) void attn_kernel(
        const int* __restrict__ adj, const float* __restrict__ el,
        const float* __restrict__ er, const float* __restrict__ ab,
        const ushort* __restrict__ hB, float* __restrict__ out)
{
    __shared__ float accbuf[32 * 256];      // 32 KB
    __shared__ float Lp[2][4][16];
    __shared__ float linv[32];
    const int t = threadIdx.x;
    const int i0 = blockIdx.x * 32;
    const int w = t >> 6, l = t & 63, q = l >> 4, m = l & 15, n = m;
    const int rg = w >> 2, jq = w & 3;
    const float bias = ab[0];
    const int row = i0 + rg * 16 + m;
    const float el_m = el[row];
    const int* adjrow = adj + (size_t)row * N + q * 8;
    const float* erp = er + q * 8;
    const ushort* hq = hB + q * 2048 + n * 8;

    f32x4 acc[16];
    #pragma unroll
    for (int ct = 0; ct < 16; ++ct) acc[ct] = (f32x4){0.f, 0.f, 0.f, 0.f};
    float lsum = 0.f;

    for (int j0 = jq * 32; j0 < N; j0 += 128) {
        const int4 a0 = *(const int4*)&adjrow[j0];
        const int4 a1 = *(const int4*)&adjrow[j0 + 4];
        const float4 e0 = *(const float4*)&erp[j0];
        const float4 e1 = *(const float4*)&erp[j0 + 4];
        float p0, p1, p2, p3, p4, p5, p6, p7, v;
        v = el_m + e0.x + bias; v = fmaxf(v, ALPHA * v); p0 = __expf(a0.x > 0 ? v : NEG_INF);
        v = el_m + e0.y + bias; v = fmaxf(v, ALPHA * v); p1 = __expf(a0.y > 0 ? v : NEG_INF);
        v = el_m + e0.z + bias; v = fmaxf(v, ALPHA * v); p2 = __expf(a0.z > 0 ? v : NEG_INF);
        v = el_m + e0.w + bias; v = fmaxf(v, ALPHA * v); p3 = __expf(a0.w > 0 ? v : NEG_INF);
        v = el_m + e1.x + bias; v = fmaxf(v, ALPHA * v); p4 = __expf(a1.x > 0 ? v : NEG_INF);
        v = el_m + e1.y + bias; v = fmaxf(v, ALPHA * v); p5 = __expf(a1.y > 0 ? v : NEG_INF);
        v = el_m + e1.z + bias; v = fmaxf(v, ALPHA * v); p6 = __expf(a1.z > 0 ? v : NEG_INF);
        v = el_m + e1.w + bias; v = fmaxf(v, ALPHA * v); p7 = __expf(a1.w > 0 ? v : NEG_INF);
        lsum += p0 + p1 + p2 + p3 + p4 + p5 + p6 + p7;
        U4BF8 pa;
        pa.u.x = pack2bf(p0, p1); pa.u.y = pack2bf(p2, p3);
        pa.u.z = pack2bf(p4, p5); pa.u.w = pack2bf(p6, p7);
        const bf16x8 af = pa.v;
        const ushort* hp = hq + (j0 >> 3) * 2048;
        #pragma unroll
        for (int ct = 0; ct < 16; ++ct) {
            const bf16x8 bf = *(const bf16x8*)&hp[ct * 128];
            acc[ct] = __builtin_amdgcn_mfma_f32_16x16x32_bf16(af, bf, acc[ct], 0, 0, 0);
        }
    }
    // row-sum: reduce over q-lanes (m, m+16, m+32, m+48)
    lsum += __shfl_xor(lsum, 16);
    lsum += __shfl_xor(lsum, 32);
    if (l < 16) Lp[rg][jq][m] = lsum;

    // combine 4 j-quarter partials through LDS
    if (jq == 0) {
        #pragma unroll
        for (int ct = 0; ct < 16; ++ct)
            #pragma unroll
            for (int r = 0; r < 4; ++r)
                accbuf[(rg * 16 + q * 4 + r) * 256 + ct * 16 + n] = acc[ct][r];
    }
    __syncthreads();
    if (jq == 1) {
        #pragma unroll
        for (int ct = 0; ct < 16; ++ct)
            #pragma unroll
            for (int r = 0; r < 4; ++r)
                accbuf[(rg * 16 + q * 4 + r) * 256 + ct * 16 + n] += acc[ct][r];
    }
    __syncthreads();
    if (jq == 2) {
        #pragma unroll
        for (int ct = 0; ct < 16; ++ct)
            #pragma unroll
            for (int r = 0; r < 4; ++r)
                accbuf[(rg * 16 + q * 4 + r) * 256 + ct * 16 + n] += acc[ct][r];
    }
    __syncthreads();
    if (jq == 3) {
        #pragma unroll
        for (int ct = 0; ct < 16; ++ct)
            #pragma unroll
            for (int r = 0; r < 4; ++r)
                accbuf[(rg * 16 + q * 4 + r) * 256 + ct * 16 + n] += acc[ct][r];
    }
    __syncthreads();
    if (t < 32) {
        const float s = Lp[t >> 4][0][t & 15] + Lp[t >> 4][1][t & 15]
                      + Lp[t >> 4][2][t & 15] + Lp[t >> 4][3][t & 15];
        linv[t] = 1.0f / s;
    }
    __syncthreads();
    // write out: 512 thr, each 16 contiguous floats of one row
    const int orow = t >> 4, c0 = (t & 15) * 16;
    const float li = linv[orow];
    #pragma unroll
    for (int ch = 0; ch < 4; ++ch) {
        float4 vv = *(const float4*)&accbuf[orow * 256 + c0 + ch * 4];
        vv.x *= li; vv.y *= li; vv.z *= li; vv.w *= li;
        *(float4*)&out[(i0 + orow) * 256 + c0 + ch * 4] = vv;
    }
}

extern "C" void kernel_launch(void* const* d_in, const int* in_sizes, int n_in,
                              void* d_out, int out_size, void* d_ws, size_t ws_size,
                              hipStream_t stream) {
    const int*   adj = (const int*)  d_in[0];
    const float* X   = (const float*)d_in[1];
    const float* W   = (const float*)d_in[2];
    const float* b   = (const float*)d_in[3];
    const float* a   = (const float*)d_in[4];
    const float* ab  = (const float*)d_in[5];
    float* out = (float*)d_out;

    ushort* hB = (ushort*)d_ws;                         // N*DOUT bf16 = 4 MB
    ushort* WB = hB + (size_t)N * DOUT;                 // DIN*DOUT bf16 = 256 KB
    float*  el = (float*)(WB + (size_t)DIN * DOUT);     // N fp32
    float*  er = el + N;                                // N fp32

    wb_kernel<<<dim3((DIN * DOUT / 4) / 256), dim3(256), 0, stream>>>(W, WB);
    h_kernel<<<dim3(N / 64), dim3(256), 0, stream>>>(X, WB, b, a, hB, el, er);
    attn_kernel<<<dim3(N / 32), dim3(512), 0, stream>>>(adj, el, er, ab, hB, out);
}

// Round 3
// 476.491 us; speedup vs baseline: 2.4580x; 1.3716x over previous
//
#include <hip/hip_runtime.h>

#define N 8192
#define DIN 512
#define DOUT 256
#define ALPHA 0.2f
#define NEG_INF -9.0e15f

typedef __attribute__((ext_vector_type(8))) short bf16x8;
typedef __attribute__((ext_vector_type(4))) float f32x4;
typedef __attribute__((ext_vector_type(4))) int   i32x4;

__device__ __forceinline__ unsigned f2bf_u(float f) {
    unsigned u = __builtin_bit_cast(unsigned, f);
    return (u + 0x7fffu + ((u >> 16) & 1u)) >> 16;   // RNE bf16
}
__device__ __forceinline__ unsigned pack2bf(float lo, float hi) {
    return f2bf_u(lo) | (f2bf_u(hi) << 16);
}
union U4BF8 { uint4 u; bf16x8 v; };

__device__ __forceinline__ void async_copy16(const ushort* g, ushort* l) {
    __builtin_amdgcn_global_load_lds(
        (const __attribute__((address_space(1))) unsigned*)g,
        (__attribute__((address_space(3))) unsigned*)l, 16, 0, 0);
}

// Kernel 0: W fp32 [512][256] -> WB bf16 in MFMA-B layout ((k>>3)*256+c)*8+(k&7).
// thread g: c = g&255, k-chunk k8 = g>>8; reads coalesced in c, writes 16B contiguous.
__global__ __launch_bounds__(256) void wb_kernel(const float* __restrict__ W,
                                                 ushort* __restrict__ WB) {
    const int g = blockIdx.x * 256 + threadIdx.x;   // 64*256 = 16384
    const int c = g & 255, k8 = g >> 8;
    const float* wp = W + (size_t)(k8 * 8) * DOUT + c;
    U4BF8 o;
    o.u.x = pack2bf(wp[0 * DOUT], wp[1 * DOUT]);
    o.u.y = pack2bf(wp[2 * DOUT], wp[3 * DOUT]);
    o.u.z = pack2bf(wp[4 * DOUT], wp[5 * DOUT]);
    o.u.w = pack2bf(wp[6 * DOUT], wp[7 * DOUT]);
    *(uint4*)(WB + (size_t)g * 8) = o.u;
}

// Kernel 1: h = X@W + b via MFMA; fused el/er; hB written bf16 in B-layout.
// grid 512 x 64 thr: one wave per block, 16 rows, all 256 cols. No LDS, no syncs.
__global__ __launch_bounds__(64) void h_kernel(
        const float* __restrict__ X, const ushort* __restrict__ WB,
        const float* __restrict__ bvec, const float* __restrict__ a,
        ushort* __restrict__ hB, float* __restrict__ el, float* __restrict__ er)
{
    const int l = threadIdx.x;
    const int q = l >> 4, n = l & 15;
    const int i0 = blockIdx.x * 16;
    f32x4 acc[16];
    #pragma unroll
    for (int ct = 0; ct < 16; ++ct) acc[ct] = (f32x4){0.f, 0.f, 0.f, 0.f};
    const float* xp = X + (size_t)(i0 + n) * DIN + q * 8;   // A: row=n, k=q*8..+8

    for (int k0 = 0; k0 < DIN; k0 += 32) {
        const float4 x0 = *(const float4*)(xp + k0);
        const float4 x1 = *(const float4*)(xp + k0 + 4);
        U4BF8 pa;
        pa.u.x = pack2bf(x0.x, x0.y); pa.u.y = pack2bf(x0.z, x0.w);
        pa.u.z = pack2bf(x1.x, x1.y); pa.u.w = pack2bf(x1.z, x1.w);
        const ushort* wbp = WB + ((k0 >> 3) + q) * 2048 + n * 8;
        bf16x8 bfr[16];
        #pragma unroll
        for (int ct = 0; ct < 16; ++ct) bfr[ct] = *(const bf16x8*)(wbp + ct * 128);
        #pragma unroll
        for (int ct = 0; ct < 16; ++ct)
            acc[ct] = __builtin_amdgcn_mfma_f32_16x16x32_bf16(pa.v, bfr[ct], acc[ct], 0, 0, 0);
    }

    float pl[4] = {0.f, 0.f, 0.f, 0.f}, pr[4] = {0.f, 0.f, 0.f, 0.f};
    const int hbase = (blockIdx.x * 2 + (q >> 1)) * 2048 + n * 8 + (q & 1) * 4;
    #pragma unroll
    for (int ct = 0; ct < 16; ++ct) {
        const float bb = bvec[ct * 16 + n];
        const float al = a[ct * 16 + n];
        const float ar = a[DOUT + ct * 16 + n];
        float v0 = acc[ct][0] + bb, v1 = acc[ct][1] + bb;
        float v2 = acc[ct][2] + bb, v3 = acc[ct][3] + bb;
        pl[0] += v0 * al; pl[1] += v1 * al; pl[2] += v2 * al; pl[3] += v3 * al;
        pr[0] += v0 * ar; pr[1] += v1 * ar; pr[2] += v2 * ar; pr[3] += v3 * ar;
        ushort4 hp;
        hp.x = (ushort)f2bf_u(v0); hp.y = (ushort)f2bf_u(v1);
        hp.z = (ushort)f2bf_u(v2); hp.w = (ushort)f2bf_u(v3);
        *(ushort4*)&hB[hbase + ct * 128] = hp;
    }
    #pragma unroll
    for (int r = 0; r < 4; ++r) {
        #pragma unroll
        for (int off = 1; off < 16; off <<= 1) {
            pl[r] += __shfl_xor(pl[r], off);
            pr[r] += __shfl_xor(pr[r], off);
        }
    }
    if (n == 0) {
        const int rowb = i0 + q * 4;
        #pragma unroll
        for (int r = 0; r < 4; ++r) { el[rowb + r] = pl[r]; er[rowb + r] = pr[r]; }
    }
}

// Kernel 2: fused masked-softmax aggregation. grid 256 x 256 thr (4 waves):
// rg = w>>1 (16 rows each), jq = w&1 (j-half of the 64-j step tile).
// hB staged to LDS (double-buffered) via global_load_lds; adj/er prefetched
// one step ahead in registers; adj loads nontemporal (keep hB in L2).
__global__ __launch_bounds__(256, 1) void attn_kernel(
        const int* __restrict__ adj, const float* __restrict__ el,
        const float* __restrict__ er, const float* __restrict__ ab,
        const ushort* __restrict__ hB, float* __restrict__ out)
{
    __shared__ ushort stage[2][16384];   // 2 x 32 KB (reused for combine)
    const int t = threadIdx.x;
    const int w = t >> 6, l = t & 63, q = l >> 4, n = l & 15;
    const int rg = w >> 1, jq = w & 1;
    const int i0 = blockIdx.x * 32;
    const int row = i0 + rg * 16 + n;
    const float elm = el[row] + ab[0];
    const int jb = jq * 32 + q * 8;                 // lane's j-offset in step tile
    const int* alp = adj + (size_t)row * N + jb;
    const float* elp = er + jb;

    f32x4 acc[16];
    #pragma unroll
    for (int ct = 0; ct < 16; ++ct) acc[ct] = (f32x4){0.f, 0.f, 0.f, 0.f};
    float lsum = 0.f;

    // prologue: stage step 0 into buf0; load adj/er for step 0
    {
        const ushort* g = hB + (size_t)(w * 8) * 512 + l * 8;
        ushort* lb = &stage[0][(w * 8) * 512];
        #pragma unroll
        for (int i = 0; i < 8; ++i) async_copy16(g + i * 512, lb + i * 512);
    }
    i32x4 ac0 = __builtin_nontemporal_load((const i32x4*)alp);
    i32x4 ac1 = __builtin_nontemporal_load((const i32x4*)(alp + 4));
    float4 ec0 = *(const float4*)elp;
    float4 ec1 = *(const float4*)(elp + 4);
    i32x4 an0 = ac0, an1 = ac1;
    float4 en0 = ec0, en1 = ec1;

    for (int s = 0; s < 128; ++s) {
        __syncthreads();                       // buf[s&1] staged; adj/er for s ready
        if (s < 127) {                         // issue step s+1 traffic (overlaps compute)
            const int J0n = (s + 1) * 64;
            const ushort* g = hB + (size_t)J0n * 256 + (size_t)(w * 8) * 512 + l * 8;
            ushort* lb = &stage[(s + 1) & 1][(w * 8) * 512];
            #pragma unroll
            for (int i = 0; i < 8; ++i) async_copy16(g + i * 512, lb + i * 512);
            an0 = __builtin_nontemporal_load((const i32x4*)(alp + J0n));
            an1 = __builtin_nontemporal_load((const i32x4*)(alp + J0n + 4));
            en0 = *(const float4*)(elp + J0n);
            en1 = *(const float4*)(elp + J0n + 4);
        }
        // P fragment: 8 j per lane (K=32 across the 4 q-groups of 16 lanes)
        float v, p0, p1, p2, p3, p4, p5, p6, p7;
        v = elm + ec0.x; v = fmaxf(v, ALPHA * v); p0 = __expf(ac0.x > 0 ? v : NEG_INF);
        v = elm + ec0.y; v = fmaxf(v, ALPHA * v); p1 = __expf(ac0.y > 0 ? v : NEG_INF);
        v = elm + ec0.z; v = fmaxf(v, ALPHA * v); p2 = __expf(ac0.z > 0 ? v : NEG_INF);
        v = elm + ec0.w; v = fmaxf(v, ALPHA * v); p3 = __expf(ac0.w > 0 ? v : NEG_INF);
        v = elm + ec1.x; v = fmaxf(v, ALPHA * v); p4 = __expf(ac1.x > 0 ? v : NEG_INF);
        v = elm + ec1.y; v = fmaxf(v, ALPHA * v); p5 = __expf(ac1.y > 0 ? v : NEG_INF);
        v = elm + ec1.z; v = fmaxf(v, ALPHA * v); p6 = __expf(ac1.z > 0 ? v : NEG_INF);
        v = elm + ec1.w; v = fmaxf(v, ALPHA * v); p7 = __expf(ac1.w > 0 ? v : NEG_INF);
        lsum += p0 + p1 + p2 + p3 + p4 + p5 + p6 + p7;
        U4BF8 pa;
        pa.u.x = pack2bf(p0, p1); pa.u.y = pack2bf(p2, p3);
        pa.u.z = pack2bf(p4, p5); pa.u.w = pack2bf(p6, p7);
        const ushort* sb = &stage[s & 1][(jq * 4 + q) * 2048 + n * 8];
        #pragma unroll
        for (int ct = 0; ct < 16; ++ct) {
            const bf16x8 bf = *(const bf16x8*)(sb + ct * 128);
            acc[ct] = __builtin_amdgcn_mfma_f32_16x16x32_bf16(pa.v, bf, acc[ct], 0, 0, 0);
        }
        ac0 = an0; ac1 = an1; ec0 = en0; ec1 = en1;
    }

    // row-sum partials: reduce over the 4 q-groups (lanes m, m+16, m+32, m+48)
    lsum += __shfl_xor(lsum, 16);
    lsum += __shfl_xor(lsum, 32);

    float* accbuf = (float*)&stage[0][0];   // 32 x 256 f32 = 32 KB
    float* LpB    = (float*)&stage[1][0];   // 4 x 16 f32
    float* linvB  = LpB + 64;               // 32 f32
    __syncthreads();
    if (l < 16) LpB[(rg * 2 + jq) * 16 + l] = lsum;
    if (jq == 0) {
        #pragma unroll
        for (int ct = 0; ct < 16; ++ct)
            #pragma unroll
            for (int r = 0; r < 4; ++r)
                accbuf[(rg * 16 + q * 4 + r) * 256 + ct * 16 + n] = acc[ct][r];
    }
    __syncthreads();
    if (jq == 1) {
        #pragma unroll
        for (int ct = 0; ct < 16; ++ct)
            #pragma unroll
            for (int r = 0; r < 4; ++r)
                accbuf[(rg * 16 + q * 4 + r) * 256 + ct * 16 + n] += acc[ct][r];
    }
    __syncthreads();
    if (t < 32)
        linvB[t] = 1.0f / (LpB[(t >> 4) * 32 + (t & 15)] + LpB[(t >> 4) * 32 + 16 + (t & 15)]);
    __syncthreads();
    const int orow = t >> 3, c0 = (t & 7) * 32;
    const float li = linvB[orow];
    #pragma unroll
    for (int ch = 0; ch < 8; ++ch) {
        float4 vv = *(const float4*)&accbuf[orow * 256 + c0 + ch * 4];
        vv.x *= li; vv.y *= li; vv.z *= li; vv.w *= li;
        *(float4*)&out[(size_t)(i0 + orow) * 256 + c0 + ch * 4] = vv;
    }
}

extern "C" void kernel_launch(void* const* d_in, const int* in_sizes, int n_in,
                              void* d_out, int out_size, void* d_ws, size_t ws_size,
                              hipStream_t stream) {
    const int*   adj = (const int*)  d_in[0];
    const float* X   = (const float*)d_in[1];
    const float* W   = (const float*)d_in[2];
    const float* b   = (const float*)d_in[3];
    const float* a   = (const float*)d_in[4];
    const float* ab  = (const float*)d_in[5];
    float* out = (float*)d_out;

    ushort* hB = (ushort*)d_ws;                         // N*DOUT bf16 = 4 MB
    ushort* WB = hB + (size_t)N * DOUT;                 // DIN*DOUT bf16 = 256 KB
    float*  el = (float*)(WB + (size_t)DIN * DOUT);     // N fp32
    float*  er = el + N;                                // N fp32

    wb_kernel<<<dim3(64), dim3(256), 0, stream>>>(W, WB);
    h_kernel<<<dim3(N / 16), dim3(64), 0, stream>>>(X, WB, b, a, hB, el, er);
    attn_kernel<<<dim3(N / 32), dim3(256), 0, stream>>>(adj, el, er, ab, hB, out);
}

// Round 4
// 458.216 us; speedup vs baseline: 2.5561x; 1.0399x over previous
//
#include <hip/hip_runtime.h>

#define N 8192
#define DIN 512
#define DOUT 256
#define ALPHA 0.2f
#define NEG_INF -9.0e15f

typedef __attribute__((ext_vector_type(8))) short bf16x8;
typedef __attribute__((ext_vector_type(4))) float f32x4;
typedef __attribute__((ext_vector_type(4))) int   i32x4;

__device__ __forceinline__ unsigned f2bf_u(float f) {
    unsigned u = __builtin_bit_cast(unsigned, f);
    return (u + 0x7fffu + ((u >> 16) & 1u)) >> 16;   // RNE bf16
}
__device__ __forceinline__ unsigned pack2bf(float lo, float hi) {
    return f2bf_u(lo) | (f2bf_u(hi) << 16);
}
union U4BF8 { uint4 u; bf16x8 v; };

__device__ __forceinline__ void async_copy16(const ushort* g, ushort* l) {
    __builtin_amdgcn_global_load_lds(
        (const __attribute__((address_space(1))) unsigned*)g,
        (__attribute__((address_space(3))) unsigned*)l, 16, 0, 0);
}

// Kernel 0: W fp32 [512][256] -> WB bf16 in MFMA-B layout ((k>>3)*256+c)*8+(k&7).
__global__ __launch_bounds__(256) void wb_kernel(const float* __restrict__ W,
                                                 ushort* __restrict__ WB) {
    const int g = blockIdx.x * 256 + threadIdx.x;   // 64*256 = 16384
    const int c = g & 255, k8 = g >> 8;
    const float* wp = W + (size_t)(k8 * 8) * DOUT + c;
    U4BF8 o;
    o.u.x = pack2bf(wp[0 * DOUT], wp[1 * DOUT]);
    o.u.y = pack2bf(wp[2 * DOUT], wp[3 * DOUT]);
    o.u.z = pack2bf(wp[4 * DOUT], wp[5 * DOUT]);
    o.u.w = pack2bf(wp[6 * DOUT], wp[7 * DOUT]);
    *(uint4*)(WB + (size_t)g * 8) = o.u;
}

// Kernel 1: h = X@W + b via MFMA, split-K across 4 waves. grid 512 x 256 thr
// (2 blocks/CU, 8 waves/CU). Each block: 16 rows; wave w covers K-range
// [w*128, w*128+128) in 4 K=32 steps; LDS reduce; fused el/er; hB bf16 B-layout.
__global__ __launch_bounds__(256) void h_kernel(
        const float* __restrict__ X, const ushort* __restrict__ WB,
        const float* __restrict__ bvec, const float* __restrict__ a,
        ushort* __restrict__ hB, float* __restrict__ el, float* __restrict__ er)
{
    __shared__ float red[4][64][65];    // [wave][lane][ct*4+r], pad 65 -> conflict-free
    __shared__ float elr[2][4][16];
    const int t = threadIdx.x;
    const int w = t >> 6, l = t & 63, q = l >> 4, n = l & 15;
    const int i0 = blockIdx.x * 16;
    f32x4 acc[16];
    #pragma unroll
    for (int ct = 0; ct < 16; ++ct) acc[ct] = (f32x4){0.f, 0.f, 0.f, 0.f};
    const float* xp = X + (size_t)(i0 + n) * DIN + q * 8;

    #pragma unroll
    for (int ks = 0; ks < 4; ++ks) {
        const int k0 = w * 128 + ks * 32;
        const float4 x0 = *(const float4*)(xp + k0);
        const float4 x1 = *(const float4*)(xp + k0 + 4);
        U4BF8 pa;
        pa.u.x = pack2bf(x0.x, x0.y); pa.u.y = pack2bf(x0.z, x0.w);
        pa.u.z = pack2bf(x1.x, x1.y); pa.u.w = pack2bf(x1.z, x1.w);
        const ushort* wbp = WB + ((k0 >> 3) + q) * 2048 + n * 8;
        bf16x8 bfr[16];
        #pragma unroll
        for (int ct = 0; ct < 16; ++ct) bfr[ct] = *(const bf16x8*)(wbp + ct * 128);
        #pragma unroll
        for (int ct = 0; ct < 16; ++ct)
            acc[ct] = __builtin_amdgcn_mfma_f32_16x16x32_bf16(pa.v, bfr[ct], acc[ct], 0, 0, 0);
    }
    #pragma unroll
    for (int ct = 0; ct < 16; ++ct)
        #pragma unroll
        for (int r = 0; r < 4; ++r) red[w][l][ct * 4 + r] = acc[ct][r];
    __syncthreads();

    // wave w finalizes ct in [w*4, w*4+4)
    float pl[4] = {0.f, 0.f, 0.f, 0.f}, pr[4] = {0.f, 0.f, 0.f, 0.f};
    const int hbase = (blockIdx.x * 2 + (q >> 1)) * 2048 + n * 8 + (q & 1) * 4;
    #pragma unroll
    for (int c2 = 0; c2 < 4; ++c2) {
        const int ct = w * 4 + c2;
        const float bb = bvec[ct * 16 + n];
        const float al = a[ct * 16 + n];
        const float ar = a[DOUT + ct * 16 + n];
        float v[4];
        #pragma unroll
        for (int r = 0; r < 4; ++r) {
            v[r] = red[0][l][ct * 4 + r] + red[1][l][ct * 4 + r]
                 + red[2][l][ct * 4 + r] + red[3][l][ct * 4 + r] + bb;
            pl[r] += v[r] * al;
            pr[r] += v[r] * ar;
        }
        ushort4 hp;
        hp.x = (ushort)f2bf_u(v[0]); hp.y = (ushort)f2bf_u(v[1]);
        hp.z = (ushort)f2bf_u(v[2]); hp.w = (ushort)f2bf_u(v[3]);
        *(ushort4*)&hB[hbase + ct * 128] = hp;
    }
    #pragma unroll
    for (int r = 0; r < 4; ++r) {
        #pragma unroll
        for (int off = 1; off < 16; off <<= 1) {
            pl[r] += __shfl_xor(pl[r], off);
            pr[r] += __shfl_xor(pr[r], off);
        }
    }
    if (n == 0) {
        #pragma unroll
        for (int r = 0; r < 4; ++r) {
            elr[0][w][q * 4 + r] = pl[r];
            elr[1][w][q * 4 + r] = pr[r];
        }
    }
    __syncthreads();
    if (t < 16) {
        el[i0 + t] = elr[0][0][t] + elr[0][1][t] + elr[0][2][t] + elr[0][3][t];
        er[i0 + t] = elr[1][0][t] + elr[1][1][t] + elr[1][2][t] + elr[1][3][t];
    }
}

// Kernel 2: fused masked-softmax aggregation. grid 256 x 512 thr (8 waves:
// rg = w>>2, jq = w&3). 128-j steps (64 total), double-buffered 64 KB hB
// stages via global_load_lds; adj/er register-prefetched 1 step ahead.
__global__ __launch_bounds__(512, 1) void attn_kernel(
        const int* __restrict__ adj, const float* __restrict__ el,
        const float* __restrict__ er, const float* __restrict__ ab,
        const ushort* __restrict__ hB, float* __restrict__ out)
{
    __shared__ ushort stage[2][32768];   // 2 x 64 KB
    const int t = threadIdx.x;
    const int w = t >> 6, l = t & 63, q = l >> 4, n = l & 15;
    const int rg = w >> 2, jq = w & 3;
    const int i0 = blockIdx.x * 32;
    const int row = i0 + rg * 16 + n;
    const float elm = el[row] + ab[0];
    const int jb = jq * 32 + q * 8;
    const int* alp = adj + (size_t)row * N + jb;
    const float* elp = er + jb;

    f32x4 acc[16];
    #pragma unroll
    for (int ct = 0; ct < 16; ++ct) acc[ct] = (f32x4){0.f, 0.f, 0.f, 0.f};
    float lsum = 0.f;

    // prologue: adj/er regs for step 0 (HBM first), then stage step 0
    i32x4 ac0 = __builtin_nontemporal_load((const i32x4*)alp);
    i32x4 ac1 = __builtin_nontemporal_load((const i32x4*)(alp + 4));
    float4 ec0 = *(const float4*)elp;
    float4 ec1 = *(const float4*)(elp + 4);
    {
        const ushort* g = hB + w * 512 + l * 8;
        ushort* lb = &stage[0][w * 512];
        #pragma unroll
        for (int i = 0; i < 8; ++i) async_copy16(g + i * 4096, lb + i * 4096);
    }

    for (int s = 0; s < 64; ++s) {
        __syncthreads();                 // buf[s&1] staged; adj/er regs for s ready
        const i32x4 aa0 = ac0, aa1 = ac1;
        const float4 ee0 = ec0, ee1 = ec1;
        if (s < 63) {                    // issue step s+1 traffic first (overlap)
            const int J0n = (s + 1) * 128;
            ac0 = __builtin_nontemporal_load((const i32x4*)(alp + J0n));
            ac1 = __builtin_nontemporal_load((const i32x4*)(alp + J0n + 4));
            ec0 = *(const float4*)(elp + J0n);
            ec1 = *(const float4*)(elp + J0n + 4);
            const ushort* g = hB + (size_t)(s + 1) * 32768 + w * 512 + l * 8;
            ushort* lb = &stage[(s + 1) & 1][w * 512];
            #pragma unroll
            for (int i = 0; i < 8; ++i) async_copy16(g + i * 4096, lb + i * 4096);
        }
        float v, p0, p1, p2, p3, p4, p5, p6, p7;
        v = elm + ee0.x; v = fmaxf(v, ALPHA * v); p0 = __expf(aa0.x > 0 ? v : NEG_INF);
        v = elm + ee0.y; v = fmaxf(v, ALPHA * v); p1 = __expf(aa0.y > 0 ? v : NEG_INF);
        v = elm + ee0.z; v = fmaxf(v, ALPHA * v); p2 = __expf(aa0.z > 0 ? v : NEG_INF);
        v = elm + ee0.w; v = fmaxf(v, ALPHA * v); p3 = __expf(aa0.w > 0 ? v : NEG_INF);
        v = elm + ee1.x; v = fmaxf(v, ALPHA * v); p4 = __expf(aa1.x > 0 ? v : NEG_INF);
        v = elm + ee1.y; v = fmaxf(v, ALPHA * v); p5 = __expf(aa1.y > 0 ? v : NEG_INF);
        v = elm + ee1.z; v = fmaxf(v, ALPHA * v); p6 = __expf(aa1.z > 0 ? v : NEG_INF);
        v = elm + ee1.w; v = fmaxf(v, ALPHA * v); p7 = __expf(aa1.w > 0 ? v : NEG_INF);
        lsum += p0 + p1 + p2 + p3 + p4 + p5 + p6 + p7;
        U4BF8 pa;
        pa.u.x = pack2bf(p0, p1); pa.u.y = pack2bf(p2, p3);
        pa.u.z = pack2bf(p4, p5); pa.u.w = pack2bf(p6, p7);
        const ushort* sb = &stage[s & 1][(jq * 4 + q) * 2048 + n * 8];
        #pragma unroll
        for (int ct = 0; ct < 16; ++ct) {
            const bf16x8 bf = *(const bf16x8*)(sb + ct * 128);
            acc[ct] = __builtin_amdgcn_mfma_f32_16x16x32_bf16(pa.v, bf, acc[ct], 0, 0, 0);
        }
    }

    lsum += __shfl_xor(lsum, 16);
    lsum += __shfl_xor(lsum, 32);

    float* accbuf = (float*)&stage[0][0];   // 32 x 272 f32 (stride-272: no pileup)
    float* LpB    = (float*)&stage[1][0];   // 8 groups x 16
    float* linvB  = LpB + 128;
    __syncthreads();                        // all compute done; LDS reusable
    if (l < 16) LpB[(rg * 4 + jq) * 16 + n] = lsum;
    if (jq == 0) {
        #pragma unroll
        for (int ct = 0; ct < 16; ++ct)
            #pragma unroll
            for (int r = 0; r < 4; ++r)
                accbuf[(rg * 16 + q * 4 + r) * 272 + ct * 16 + n] = acc[ct][r];
    }
    __syncthreads();
    if (jq == 1) {
        #pragma unroll
        for (int ct = 0; ct < 16; ++ct)
            #pragma unroll
            for (int r = 0; r < 4; ++r)
                accbuf[(rg * 16 + q * 4 + r) * 272 + ct * 16 + n] += acc[ct][r];
    }
    __syncthreads();
    if (jq == 2) {
        #pragma unroll
        for (int ct = 0; ct < 16; ++ct)
            #pragma unroll
            for (int r = 0; r < 4; ++r)
                accbuf[(rg * 16 + q * 4 + r) * 272 + ct * 16 + n] += acc[ct][r];
    }
    __syncthreads();
    if (jq == 3) {
        #pragma unroll
        for (int ct = 0; ct < 16; ++ct)
            #pragma unroll
            for (int r = 0; r < 4; ++r)
                accbuf[(rg * 16 + q * 4 + r) * 272 + ct * 16 + n] += acc[ct][r];
    }
    __syncthreads();
    if (t < 32) {
        const int rr = t >> 4, m = t & 15;
        linvB[t] = 1.0f / (LpB[(rr * 4 + 0) * 16 + m] + LpB[(rr * 4 + 1) * 16 + m]
                         + LpB[(rr * 4 + 2) * 16 + m] + LpB[(rr * 4 + 3) * 16 + m]);
    }
    __syncthreads();
    const int orow = t >> 4, c0 = (t & 15) * 16;
    const float li = linvB[orow];
    #pragma unroll
    for (int ch = 0; ch < 4; ++ch) {
        float4 vv = *(const float4*)&accbuf[orow * 272 + c0 + ch * 4];
        vv.x *= li; vv.y *= li; vv.z *= li; vv.w *= li;
        *(float4*)&out[(size_t)(i0 + orow) * 256 + c0 + ch * 4] = vv;
    }
}

extern "C" void kernel_launch(void* const* d_in, const int* in_sizes, int n_in,
                              void* d_out, int out_size, void* d_ws, size_t ws_size,
                              hipStream_t stream) {
    const int*   adj = (const int*)  d_in[0];
    const float* X   = (const float*)d_in[1];
    const float* W   = (const float*)d_in[2];
    const float* b   = (const float*)d_in[3];
    const float* a   = (const float*)d_in[4];
    const float* ab  = (const float*)d_in[5];
    float* out = (float*)d_out;

    ushort* hB = (ushort*)d_ws;                         // N*DOUT bf16 = 4 MB
    ushort* WB = hB + (size_t)N * DOUT;                 // DIN*DOUT bf16 = 256 KB
    float*  el = (float*)(WB + (size_t)DIN * DOUT);     // N fp32
    float*  er = el + N;                                // N fp32

    wb_kernel<<<dim3(64), dim3(256), 0, stream>>>(W, WB);
    h_kernel<<<dim3(N / 16), dim3(256), 0, stream>>>(X, WB, b, a, hB, el, er);
    attn_kernel<<<dim3(N / 32), dim3(512), 0, stream>>>(adj, el, er, ab, hB, out);
}

// Round 5
// 418.790 us; speedup vs baseline: 2.7967x; 1.0941x over previous
//
#include <hip/hip_runtime.h>

#define N 8192
#define DIN 512
#define DOUT 256
#define ALPHA 0.2f
#define NEG_INF -9.0e15f

typedef __attribute__((ext_vector_type(8))) short bf16x8;
typedef __attribute__((ext_vector_type(4))) float f32x4;
typedef __attribute__((ext_vector_type(4))) int   i32x4;

__device__ __forceinline__ unsigned f2bf_u(float f) {
    unsigned u = __builtin_bit_cast(unsigned, f);
    return (u + 0x7fffu + ((u >> 16) & 1u)) >> 16;   // RNE bf16
}
__device__ __forceinline__ unsigned pack2bf(float lo, float hi) {
    return f2bf_u(lo) | (f2bf_u(hi) << 16);
}
union U4BF8 { uint4 u; bf16x8 v; };

__device__ __forceinline__ void async_copy16(const ushort* g, ushort* l) {
    __builtin_amdgcn_global_load_lds(
        (const __attribute__((address_space(1))) unsigned*)g,
        (__attribute__((address_space(3))) unsigned*)l, 16, 0, 0);
}

// Kernel 0: W fp32 [512][256] -> WB bf16 in MFMA-B layout ((k>>3)*256+c)*8+(k&7).
__global__ __launch_bounds__(256) void wb_kernel(const float* __restrict__ W,
                                                 ushort* __restrict__ WB) {
    const int g = blockIdx.x * 256 + threadIdx.x;   // 64*256 = 16384
    const int c = g & 255, k8 = g >> 8;
    const float* wp = W + (size_t)(k8 * 8) * DOUT + c;
    U4BF8 o;
    o.u.x = pack2bf(wp[0 * DOUT], wp[1 * DOUT]);
    o.u.y = pack2bf(wp[2 * DOUT], wp[3 * DOUT]);
    o.u.z = pack2bf(wp[4 * DOUT], wp[5 * DOUT]);
    o.u.w = pack2bf(wp[6 * DOUT], wp[7 * DOUT]);
    *(uint4*)(WB + (size_t)g * 8) = o.u;
}

// Kernel 1: h = X@W + b via MFMA, split-K across 4 waves (unchanged from R4).
__global__ __launch_bounds__(256) void h_kernel(
        const float* __restrict__ X, const ushort* __restrict__ WB,
        const float* __restrict__ bvec, const float* __restrict__ a,
        ushort* __restrict__ hB, float* __restrict__ el, float* __restrict__ er)
{
    __shared__ float red[4][64][65];
    __shared__ float elr[2][4][16];
    const int t = threadIdx.x;
    const int w = t >> 6, l = t & 63, q = l >> 4, n = l & 15;
    const int i0 = blockIdx.x * 16;
    f32x4 acc[16];
    #pragma unroll
    for (int ct = 0; ct < 16; ++ct) acc[ct] = (f32x4){0.f, 0.f, 0.f, 0.f};
    const float* xp = X + (size_t)(i0 + n) * DIN + q * 8;

    #pragma unroll
    for (int ks = 0; ks < 4; ++ks) {
        const int k0 = w * 128 + ks * 32;
        const float4 x0 = *(const float4*)(xp + k0);
        const float4 x1 = *(const float4*)(xp + k0 + 4);
        U4BF8 pa;
        pa.u.x = pack2bf(x0.x, x0.y); pa.u.y = pack2bf(x0.z, x0.w);
        pa.u.z = pack2bf(x1.x, x1.y); pa.u.w = pack2bf(x1.z, x1.w);
        const ushort* wbp = WB + ((k0 >> 3) + q) * 2048 + n * 8;
        bf16x8 bfr[16];
        #pragma unroll
        for (int ct = 0; ct < 16; ++ct) bfr[ct] = *(const bf16x8*)(wbp + ct * 128);
        #pragma unroll
        for (int ct = 0; ct < 16; ++ct)
            acc[ct] = __builtin_amdgcn_mfma_f32_16x16x32_bf16(pa.v, bfr[ct], acc[ct], 0, 0, 0);
    }
    #pragma unroll
    for (int ct = 0; ct < 16; ++ct)
        #pragma unroll
        for (int r = 0; r < 4; ++r) red[w][l][ct * 4 + r] = acc[ct][r];
    __syncthreads();

    float pl[4] = {0.f, 0.f, 0.f, 0.f}, pr[4] = {0.f, 0.f, 0.f, 0.f};
    const int hbase = (blockIdx.x * 2 + (q >> 1)) * 2048 + n * 8 + (q & 1) * 4;
    #pragma unroll
    for (int c2 = 0; c2 < 4; ++c2) {
        const int ct = w * 4 + c2;
        const float bb = bvec[ct * 16 + n];
        const float al = a[ct * 16 + n];
        const float ar = a[DOUT + ct * 16 + n];
        float v[4];
        #pragma unroll
        for (int r = 0; r < 4; ++r) {
            v[r] = red[0][l][ct * 4 + r] + red[1][l][ct * 4 + r]
                 + red[2][l][ct * 4 + r] + red[3][l][ct * 4 + r] + bb;
            pl[r] += v[r] * al;
            pr[r] += v[r] * ar;
        }
        ushort4 hp;
        hp.x = (ushort)f2bf_u(v[0]); hp.y = (ushort)f2bf_u(v[1]);
        hp.z = (ushort)f2bf_u(v[2]); hp.w = (ushort)f2bf_u(v[3]);
        *(ushort4*)&hB[hbase + ct * 128] = hp;
    }
    #pragma unroll
    for (int r = 0; r < 4; ++r) {
        #pragma unroll
        for (int off = 1; off < 16; off <<= 1) {
            pl[r] += __shfl_xor(pl[r], off);
            pr[r] += __shfl_xor(pr[r], off);
        }
    }
    if (n == 0) {
        #pragma unroll
        for (int r = 0; r < 4; ++r) {
            elr[0][w][q * 4 + r] = pl[r];
            elr[1][w][q * 4 + r] = pr[r];
        }
    }
    __syncthreads();
    if (t < 16) {
        el[i0 + t] = elr[0][0][t] + elr[0][1][t] + elr[0][2][t] + elr[0][3][t];
        er[i0 + t] = elr[1][0][t] + elr[1][1][t] + elr[1][2][t] + elr[1][3][t];
    }
}

// Kernel 2: attention partials. Block = 128 rows x 2048 j (j-quarter).
// grid 256 = 64 row-blocks x 4 jq. 8 waves: wave w owns rows w*16..+16, full
// 128-j steps (16 steps). hB j-tiles (64 KB) double-buffered in LDS via
// global_load_lds, shared by all waves; er quarter staged once (8 KB).
// adj register-prefetched (nontemporal). Unnormalized partials + row sums out.
__global__ __launch_bounds__(512, 1) void attn_kernel(
        const int* __restrict__ adj, const float* __restrict__ el,
        const float* __restrict__ er, const float* __restrict__ ab,
        const ushort* __restrict__ hB, float* __restrict__ pout,
        float* __restrict__ plsum)
{
    __shared__ ushort stage[2][32768];   // 2 x 64 KB
    __shared__ float ers[2048];          // 8 KB
    const int t = threadIdx.x;
    const int w = t >> 6, l = t & 63, q = l >> 4, n = l & 15;
    const int rb = blockIdx.x >> 2, jq = blockIdx.x & 3;
    const int j0 = jq * 2048;
    const int row = rb * 128 + w * 16 + n;
    const float elm = el[row] + ab[0];
    const int* alp = adj + (size_t)row * N + j0 + q * 8;

    f32x4 acc[16];
    #pragma unroll
    for (int ct = 0; ct < 16; ++ct) acc[ct] = (f32x4){0.f, 0.f, 0.f, 0.f};
    float lsum = 0.f;

    // prologue: er quarter -> LDS; adj regs for step 0; hB step-0 tile -> stage[0]
    *(float4*)&ers[t * 4] = *(const float4*)&er[j0 + t * 4];
    i32x4 a[8];
    #pragma unroll
    for (int kg = 0; kg < 4; ++kg) {
        a[2 * kg]     = __builtin_nontemporal_load((const i32x4*)(alp + kg * 32));
        a[2 * kg + 1] = __builtin_nontemporal_load((const i32x4*)(alp + kg * 32 + 4));
    }
    {
        const ushort* g = hB + (size_t)j0 * 256 + t * 8;
        ushort* lb = &stage[0][t * 8];
        #pragma unroll
        for (int i = 0; i < 8; ++i) async_copy16(g + i * 4096, lb + i * 4096);
    }

    for (int s = 0; s < 16; ++s) {
        __syncthreads();                 // stage[s&1] + ers ready; adj regs for s held
        if (s < 15) {                    // next hB tile first (no reg pressure)
            const ushort* g = hB + (size_t)(j0 + (s + 1) * 128) * 256 + t * 8;
            ushort* lb = &stage[(s + 1) & 1][t * 8];
            #pragma unroll
            for (int i = 0; i < 8; ++i) async_copy16(g + i * 4096, lb + i * 4096);
        }
        // A-fragments: 4 K-groups x 8 j per lane
        U4BF8 pa[4];
        #pragma unroll
        for (int kg = 0; kg < 4; ++kg) {
            const float4 e0 = *(const float4*)&ers[s * 128 + kg * 32 + q * 8];
            const float4 e1 = *(const float4*)&ers[s * 128 + kg * 32 + q * 8 + 4];
            const i32x4 a0 = a[2 * kg], a1 = a[2 * kg + 1];
            float v, p0, p1, p2, p3, p4, p5, p6, p7;
            v = elm + e0.x; v = fmaxf(v, ALPHA * v); p0 = __expf(a0.x > 0 ? v : NEG_INF);
            v = elm + e0.y; v = fmaxf(v, ALPHA * v); p1 = __expf(a0.y > 0 ? v : NEG_INF);
            v = elm + e0.z; v = fmaxf(v, ALPHA * v); p2 = __expf(a0.z > 0 ? v : NEG_INF);
            v = elm + e0.w; v = fmaxf(v, ALPHA * v); p3 = __expf(a0.w > 0 ? v : NEG_INF);
            v = elm + e1.x; v = fmaxf(v, ALPHA * v); p4 = __expf(a1.x > 0 ? v : NEG_INF);
            v = elm + e1.y; v = fmaxf(v, ALPHA * v); p5 = __expf(a1.y > 0 ? v : NEG_INF);
            v = elm + e1.z; v = fmaxf(v, ALPHA * v); p6 = __expf(a1.z > 0 ? v : NEG_INF);
            v = elm + e1.w; v = fmaxf(v, ALPHA * v); p7 = __expf(a1.w > 0 ? v : NEG_INF);
            lsum += p0 + p1 + p2 + p3 + p4 + p5 + p6 + p7;
            pa[kg].u.x = pack2bf(p0, p1); pa[kg].u.y = pack2bf(p2, p3);
            pa[kg].u.z = pack2bf(p4, p5); pa[kg].u.w = pack2bf(p6, p7);
        }
        if (s < 15) {                    // adj regs for step s+1
            const int* ap = alp + (s + 1) * 128;
            #pragma unroll
            for (int kg = 0; kg < 4; ++kg) {
                a[2 * kg]     = __builtin_nontemporal_load((const i32x4*)(ap + kg * 32));
                a[2 * kg + 1] = __builtin_nontemporal_load((const i32x4*)(ap + kg * 32 + 4));
            }
        }
        #pragma unroll
        for (int kg = 0; kg < 4; ++kg) {
            const ushort* sb = &stage[s & 1][(kg * 4 + q) * 2048 + n * 8];
            #pragma unroll
            for (int ct = 0; ct < 16; ++ct) {
                const bf16x8 bf = *(const bf16x8*)(sb + ct * 128);
                acc[ct] = __builtin_amdgcn_mfma_f32_16x16x32_bf16(pa[kg].v, bf, acc[ct], 0, 0, 0);
            }
        }
    }

    // row sums: reduce across the 4 q-groups holding row n
    lsum += __shfl_xor(lsum, 16);
    lsum += __shfl_xor(lsum, 32);
    if (l < 16) plsum[(size_t)jq * N + row] = lsum;

    // unnormalized partial tile: rows rb*128 + w*16 + q*4+r, col ct*16+n
    float* pb = pout + ((size_t)jq * N + rb * 128 + w * 16 + q * 4) * 256 + n;
    #pragma unroll
    for (int ct = 0; ct < 16; ++ct)
        #pragma unroll
        for (int r = 0; r < 4; ++r)
            __builtin_nontemporal_store(acc[ct][r], pb + (size_t)r * 256 + ct * 16);
}

// Kernel 3: combine j-quarter partials + normalize. grid 2048 x 256.
__global__ __launch_bounds__(256) void combine_kernel(
        const float* __restrict__ pout, const float* __restrict__ plsum,
        float* __restrict__ out)
{
    const int t = threadIdx.x;
    const int row = blockIdx.x * 4 + (t >> 6);
    const int c = (t & 63) * 4;
    const size_t idx = (size_t)row * 256 + c;
    const size_t qs = (size_t)N * 256;
    float4 v0 = *(const float4*)&pout[idx];
    float4 v1 = *(const float4*)&pout[idx + qs];
    float4 v2 = *(const float4*)&pout[idx + 2 * qs];
    float4 v3 = *(const float4*)&pout[idx + 3 * qs];
    const float li = 1.0f / (plsum[row] + plsum[N + row]
                           + plsum[2 * N + row] + plsum[3 * N + row]);
    float4 o;
    o.x = (v0.x + v1.x + v2.x + v3.x) * li;
    o.y = (v0.y + v1.y + v2.y + v3.y) * li;
    o.z = (v0.z + v1.z + v2.z + v3.z) * li;
    o.w = (v0.w + v1.w + v2.w + v3.w) * li;
    *(float4*)&out[idx] = o;
}

extern "C" void kernel_launch(void* const* d_in, const int* in_sizes, int n_in,
                              void* d_out, int out_size, void* d_ws, size_t ws_size,
                              hipStream_t stream) {
    const int*   adj = (const int*)  d_in[0];
    const float* X   = (const float*)d_in[1];
    const float* W   = (const float*)d_in[2];
    const float* b   = (const float*)d_in[3];
    const float* a   = (const float*)d_in[4];
    const float* ab  = (const float*)d_in[5];
    float* out = (float*)d_out;

    ushort* hB    = (ushort*)d_ws;                        // 4 MB
    ushort* WB    = hB + (size_t)N * DOUT;                // 256 KB
    float*  el    = (float*)(WB + (size_t)DIN * DOUT);    // 32 KB
    float*  er    = el + N;                               // 32 KB
    float*  plsum = er + N;                               // 4*N fp32 = 128 KB
    float*  pout  = plsum + 4 * N;                        // 4*N*256 fp32 = 32 MB

    wb_kernel<<<dim3(64), dim3(256), 0, stream>>>(W, WB);
    h_kernel<<<dim3(N / 16), dim3(256), 0, stream>>>(X, WB, b, a, hB, el, er);
    attn_kernel<<<dim3(256), dim3(512), 0, stream>>>(adj, el, er, ab, hB, pout, plsum);
    combine_kernel<<<dim3(N / 4), dim3(256), 0, stream>>>(pout, plsum, out);
}